// Round 7
// baseline (1644.793 us; speedup 1.0000x reference)
//
#include <hip/hip_runtime.h>
#include <hip/hip_bf16.h>
#include <cstdint>

#define DM   1024
#define DFF  2048
#define NH   16
#define DK   64
#define BBATCH 512
#define LSEQ 60
#define M_TOK (BBATCH*LSEQ)   // 30720
#define NQKV (3*DM)           // 3072
#define NTM  120              // M_TOK / 256

typedef __attribute__((ext_vector_type(8))) short bf16x8;
typedef __attribute__((ext_vector_type(4))) float f32x4;
typedef __attribute__((ext_vector_type(8))) unsigned short u16x8;
typedef __attribute__((ext_vector_type(4))) unsigned short u16x4;

__device__ __forceinline__ unsigned short f2bf(float f) {
  union { float f; unsigned u; } x; x.f = f;
  unsigned r = x.u + 0x7fffu + ((x.u >> 16) & 1u);   // RNE
  return (unsigned short)(r >> 16);
}
__device__ __forceinline__ float bf2f(unsigned short u) {
  union { unsigned u; float f; } x; x.u = ((unsigned)u) << 16;
  return x.f;
}

__device__ __forceinline__ void gload_lds16(const void* g, void* l) {
  __builtin_amdgcn_global_load_lds(
      (const __attribute__((address_space(1))) unsigned int*)g,
      (__attribute__((address_space(3))) unsigned int*)l, 16, 0, 0);
}

template<int MO,int NO>
__device__ __forceinline__ void mf8(f32x4 (&acc)[8][4], const bf16x8 (&a)[4][2],
                                    const bf16x8 (&b)[2][2]) {
#pragma unroll
  for (int m=0;m<4;++m)
#pragma unroll
    for (int n=0;n<2;++n)
#pragma unroll
      for (int ks=0;ks<2;++ks)
        acc[MO+m][NO+n] = __builtin_amdgcn_mfma_f32_16x16x32_bf16(a[m][ks], b[n][ks], acc[MO+m][NO+n], 0,0,0);
}

#define A0S 0
#define A1S 16384
#define B0S 32768
#define B1S 49152

// 256x256 tile, BK=64, 8 waves (2Mx4N), 2-K-tile 8-phase schedule with
// one-phase register read-ahead. launch_bounds(512,1): occupancy is
// LDS-limited to 1 block/CU regardless (128 KiB), so don't cap the
// allocator at 256 regs — r5/r6 post-mortem: the 256 cap forced a
// ~26-reg spill (WRITE_SIZE 184MB -> 1.2GB scratch traffic).
// MODE 0: C bf16   MODE 2: C bf16 = relu(acc)
// MODE 3: C bf16 = acc + bf16_residual[row*ldc+col]
template<int MODE>
__global__ __launch_bounds__(512, 1)
void gemm256(const unsigned short* __restrict__ A, int lda,
             const unsigned short* __restrict__ B, int ldb,
             void* __restrict__ Cv, int ldc,
             const void* __restrict__ Resv, int K) {
  __shared__ unsigned short sm[65536];
  const int t  = threadIdx.x;
  const int l  = t & 63, w = t >> 6;
  const int lo = l & 15, hi = l >> 4;
  const int wr = w >> 2, wc = w & 3;
  const int swz = (lo & 7) << 4;

  const int nwg = (int)gridDim.x;
  int wg = (int)blockIdx.x;
  wg = (wg & 7) * (nwg >> 3) + (wg >> 3);
  const int ng  = wg / (NTM*4);
  const int rem = wg - ng*(NTM*4);
  const long row0 = (long)(rem >> 2) * 256;
  const long col0 = (long)(ng*4 + (rem & 3)) * 256;

  const int srow = w*16 + (l>>3);
  const int scol = ((l & 7) ^ (l >> 3)) * 8;
  const unsigned short* pa = A + (size_t)(row0 + srow)*lda + scol;
  const unsigned short* pb = B + (size_t)(col0 + srow)*ldb + scol;
  const size_t ldaj = (size_t)8*lda,  ldah = (size_t)128*lda;
  const size_t ldbj = (size_t)8*ldb,  ldbh = (size_t)128*ldb;
  const int dls = (w*2)*512;

#define STAGE_A(bufS, h, kt) do { \
    const unsigned short* _s = pa + (size_t)(h)*ldah + (size_t)(kt)*64; \
    gload_lds16(_s,        &sm[(bufS) + (h)*8192 + dls]); \
    gload_lds16(_s + ldaj, &sm[(bufS) + (h)*8192 + dls + 512]); \
  } while(0)
#define STAGE_B(bufS, h, kt) do { \
    const unsigned short* _s = pb + (size_t)(h)*ldbh + (size_t)(kt)*64; \
    gload_lds16(_s,        &sm[(bufS) + (h)*8192 + dls]); \
    gload_lds16(_s + ldbj, &sm[(bufS) + (h)*8192 + dls + 512]); \
  } while(0)
#define RD_A(dst, bufS, mbase) do { \
  _Pragma("unroll") for (int m=0;m<4;++m) \
  _Pragma("unroll") for (int ks=0;ks<2;++ks) \
    dst[m][ks] = *(const bf16x8*)((const char*)sm + (bufS)*2 + \
        (wr*128 + ((mbase)+m)*16 + lo)*128 + ((ks*64 + hi*16) ^ swz)); \
  } while(0)
#define RD_B(dst, bufS, nbase) do { \
  _Pragma("unroll") for (int n=0;n<2;++n) \
  _Pragma("unroll") for (int ks=0;ks<2;++ks) \
    dst[n][ks] = *(const bf16x8*)((const char*)sm + (bufS)*2 + \
        (wc*64 + ((nbase)+n)*16 + lo)*128 + ((ks*64 + hi*16) ^ swz)); \
  } while(0)
#define BAR __builtin_amdgcn_s_barrier()
#define VMC(n) asm volatile("s_waitcnt vmcnt(" #n ")" ::: "memory")
#define P1S __builtin_amdgcn_s_setprio(1)
#define P0S __builtin_amdgcn_s_setprio(0)

  f32x4 acc[8][4];
#pragma unroll
  for (int m=0;m<8;++m)
#pragma unroll
    for (int n=0;n<4;++n) acc[m][n] = (f32x4){0.f,0.f,0.f,0.f};

  const int nkt = K >> 6;
  bf16x8 aA[4][2], aB[4][2], bX[2][2], bY[2][2];

  // prologue: stage tiles 0,1; wait tile0; preload Q1 frags (a0,b0)
  STAGE_A(A0S, 0, 0); STAGE_A(A0S, 1, 0);
  STAGE_B(B0S, 0, 0); STAGE_B(B0S, 1, 0);
  STAGE_A(A1S, 0, 1); STAGE_A(A1S, 1, 1);
  STAGE_B(B1S, 0, 1); STAGE_B(B1S, 1, 1);
  VMC(8);
  BAR;
  RD_A(aA, A0S, 0); RD_B(bX, B0S, 0);

  for (int kt = 0; kt + 2 < nkt; kt += 2) {
    // P1: read b2; MFMA Q1(a0,b0)
    RD_B(bY, B0S, 2);
    BAR;
    P1S; mf8<0,0>(acc, aA, bX); P0S; BAR;
    // P2: read a1; MFMA Q2(a0,b2)
    RD_A(aB, A0S, 4);
    BAR;
    P1S; mf8<0,2>(acc, aA, bY); P0S; BAR;
    // P3: stage B0S.h0(kt+2); drain prev A1S/B1S stages; MFMA Q3(a1,b0)
    STAGE_B(B0S, 0, kt+2);
    VMC(2);
    BAR;
    P1S; mf8<4,0>(acc, aB, bX); P0S; BAR;
    // P4: read c0,d0 (tile kt+1); stage B0S.h1; MFMA Q4(a1,b2)
    RD_A(aA, A1S, 0); RD_B(bX, B1S, 0);
    STAGE_B(B0S, 1, kt+2);
    BAR;
    P1S; mf8<4,2>(acc, aB, bY); P0S; BAR;
    // P5: read d2; stage A0S.h0; MFMA Q5(c0,d0)
    RD_B(bY, B1S, 2);
    STAGE_A(A0S, 0, kt+2);
    BAR;
    P1S; mf8<0,0>(acc, aA, bX); P0S; BAR;
    // P6: read c1; stage A0S.h1; MFMA Q6(c0,d2)
    RD_A(aB, A1S, 4);
    STAGE_A(A0S, 1, kt+2);
    BAR;
    P1S; mf8<0,2>(acc, aA, bY); P0S; BAR;
    // P7: stage B1S(kt+3); drain A0S/B0S(kt+2) stages; MFMA Q7(c1,d0)
    STAGE_B(B1S, 0, kt+3); STAGE_B(B1S, 1, kt+3);
    VMC(4);
    BAR;
    P1S; mf8<4,0>(acc, aB, bX); P0S; BAR;
    // P8: read a0',b0' (tile kt+2); stage A1S(kt+3); MFMA Q8(c1,d2)
    RD_A(aA, A0S, 0); RD_B(bX, B0S, 0);
    STAGE_A(A1S, 0, kt+3); STAGE_A(A1S, 1, kt+3);
    BAR;
    P1S; mf8<4,2>(acc, aB, bY); P0S; BAR;
  }

  // peel: last two tiles (A0S/B0S = nkt-2, A1S/B1S = nkt-1)
  {
    RD_B(bY, B0S, 2);
    BAR; P1S; mf8<0,0>(acc, aA, bX); P0S; BAR;
    RD_A(aB, A0S, 4);
    BAR; P1S; mf8<0,2>(acc, aA, bY); P0S; BAR;
    VMC(0);
    BAR; P1S; mf8<4,0>(acc, aB, bX); P0S; BAR;
    RD_A(aA, A1S, 0); RD_B(bX, B1S, 0);
    BAR; P1S; mf8<4,2>(acc, aB, bY); P0S; BAR;
    RD_B(bY, B1S, 2);
    BAR; P1S; mf8<0,0>(acc, aA, bX); P0S; BAR;
    RD_A(aB, A1S, 4);
    BAR; P1S; mf8<0,2>(acc, aA, bY); P0S; BAR;
    BAR; P1S; mf8<4,0>(acc, aB, bX); P0S; BAR;
    P1S; mf8<4,2>(acc, aB, bY); P0S;
  }

  // epilogue
#pragma unroll
  for (int m=0;m<8;++m) {
#pragma unroll
    for (int r=0;r<4;++r) {
      const long row = row0 + wr*128 + m*16 + hi*4 + r;
      const size_t base = (size_t)row * ldc;
#pragma unroll
      for (int n=0;n<4;++n) {
        const long col = col0 + wc*64 + n*16 + lo;
        const float v = acc[m][n][r];
        if (MODE == 0) {
          ((unsigned short*)Cv)[base + col] = f2bf(v);
        } else if (MODE == 2) {
          ((unsigned short*)Cv)[base + col] = f2bf(v > 0.f ? v : 0.f);
        } else {
          const unsigned short* R16 = (const unsigned short*)Resv;
          ((unsigned short*)Cv)[base + col] = f2bf(v + bf2f(R16[base + col]));
        }
      }
    }
  }
#undef STAGE_A
#undef STAGE_B
#undef RD_A
#undef RD_B
#undef BAR
#undef VMC
#undef P1S
#undef P0S
}

// One block per (b,h). qkv: [M_TOK][3072] bf16 (Q|K|V). ctx written in-place over Q cols.
__global__ __launch_bounds__(256)
void attn_kernel(unsigned short* qkv, const float* __restrict__ att_sig,
                 float* __restrict__ loss_part) {
  __shared__ unsigned short qs[64*64], ks[64*64], vts[64*64], as2[64*64];
  __shared__ float red[4];
  const int bid = blockIdx.x;
  const int b = bid >> 4, h = bid & 15;
  const int t = threadIdx.x;
  const int l = t & 63, w = t >> 6, lo = l & 15, hi = l >> 4;

#pragma unroll
  for (int p=0;p<2;++p) {
    int row = p*32 + (t>>3);
    int d0  = (t&7)*8;
    u16x8 zq = {0,0,0,0,0,0,0,0}; u16x8 zk = zq; u16x8 zv = zq;
    if (row < LSEQ) {
      size_t g = (size_t)(b*LSEQ + row)*NQKV + h*DK + d0;
      zq = *(const u16x8*)(qkv + g);
      zk = *(const u16x8*)(qkv + g + DM);
      zv = *(const u16x8*)(qkv + g + 2*DM);
    }
    *(u16x8*)&qs[row*64 + d0] = zq;
    *(u16x8*)&ks[row*64 + d0] = zk;
#pragma unroll
    for (int j=0;j<8;++j) vts[(d0+j)*64 + row] = zv[j];
  }
  __syncthreads();

  f32x4 zero4 = {0.f,0.f,0.f,0.f};
  f32x4 sacc[4];
#pragma unroll
  for (int ct=0;ct<4;++ct) sacc[ct] = zero4;
  bf16x8 aq[2];
  aq[0] = *(const bf16x8*)&qs[(w*16+lo)*64 + hi*8];
  aq[1] = *(const bf16x8*)&qs[(w*16+lo)*64 + 32 + hi*8];
#pragma unroll
  for (int ct=0;ct<4;++ct)
#pragma unroll
    for (int kk=0;kk<2;++kk) {
      bf16x8 bk = *(const bf16x8*)&ks[(ct*16+lo)*64 + kk*32 + hi*8];
      sacc[ct] = __builtin_amdgcn_mfma_f32_16x16x32_bf16(aq[kk], bk, sacc[ct], 0,0,0);
    }

  float lloss = 0.f;
  const float SC = 0.125f;
#pragma unroll
  for (int r=0;r<4;++r) {
    int row = w*16 + hi*4 + r;
    float v0 = sacc[0][r]*SC, v1 = sacc[1][r]*SC, v2 = sacc[2][r]*SC;
    float v3 = (lo < 12) ? sacc[3][r]*SC : -__builtin_inff();
    float mx = fmaxf(fmaxf(v0,v1), fmaxf(v2,v3));
#pragma unroll
    for (int d=1; d<16; d<<=1) mx = fmaxf(mx, __shfl_xor(mx, d, 64));
    float p0=__expf(v0-mx), p1=__expf(v1-mx), p2=__expf(v2-mx), p3=__expf(v3-mx);
    float sm = p0+p1+p2+p3;
#pragma unroll
    for (int d=1; d<16; d<<=1) sm += __shfl_xor(sm, d, 64);
    float inv = 1.0f / sm;
    float a0=p0*inv, a1=p1*inv, a2=p2*inv, a3=p3*inv;
    if (row < LSEQ) {
      float df;
      df = a0 - att_sig[row*LSEQ + lo];       lloss += df*df;
      df = a1 - att_sig[row*LSEQ + 16 + lo];  lloss += df*df;
      df = a2 - att_sig[row*LSEQ + 32 + lo];  lloss += df*df;
      if (lo < 12) { df = a3 - att_sig[row*LSEQ + 48 + lo]; lloss += df*df; }
    }
    as2[row*64 + lo]      = f2bf(a0);
    as2[row*64 + 16 + lo] = f2bf(a1);
    as2[row*64 + 32 + lo] = f2bf(a2);
    as2[row*64 + 48 + lo] = f2bf(a3);
  }
  __syncthreads();

  f32x4 cacc[4];
#pragma unroll
  for (int n=0;n<4;++n) cacc[n] = zero4;
  bf16x8 ap[2];
  ap[0] = *(const bf16x8*)&as2[(w*16+lo)*64 + hi*8];
  ap[1] = *(const bf16x8*)&as2[(w*16+lo)*64 + 32 + hi*8];
#pragma unroll
  for (int n=0;n<4;++n)
#pragma unroll
    for (int kk=0;kk<2;++kk) {
      bf16x8 bv = *(const bf16x8*)&vts[(n*16+lo)*64 + kk*32 + hi*8];
      cacc[n] = __builtin_amdgcn_mfma_f32_16x16x32_bf16(ap[kk], bv, cacc[n], 0,0,0);
    }
#pragma unroll
  for (int r=0;r<4;++r) {
    int row = w*16 + hi*4 + r;
    if (row < LSEQ) {
      size_t g = (size_t)(b*LSEQ + row)*NQKV + h*DK;
#pragma unroll
      for (int n=0;n<4;++n)
        qkv[g + n*16 + lo] = f2bf(cacc[n][r]);
    }
  }

#pragma unroll
  for (int d=1; d<64; d<<=1) lloss += __shfl_xor(lloss, d, 64);
  if (l == 0) red[w] = lloss;
  __syncthreads();
  if (t == 0) loss_part[bid] = red[0]+red[1]+red[2]+red[3];
}

__global__ __launch_bounds__(256)
void reduce_loss(const float* __restrict__ part, float* __restrict__ out) {
  __shared__ float red[4];
  float s = 0.f;
  for (int i = threadIdx.x; i < BBATCH*NH; i += 256) s += part[i];
#pragma unroll
  for (int d=1; d<64; d<<=1) s += __shfl_xor(s, d, 64);
  if ((threadIdx.x & 63) == 0) red[threadIdx.x >> 6] = s;
  __syncthreads();
  if (threadIdx.x == 0) out[0] = red[0]+red[1]+red[2]+red[3];
}

// Row LayerNorm, bf16 input. OUTF=0: write bf16; OUTF=1: write fp32.
template<int OUTF>
__global__ __launch_bounds__(256)
void ln_bf(const unsigned short* __restrict__ in, const float* __restrict__ gw,
           const float* __restrict__ gb, void* __restrict__ out) {
  __shared__ float red[4];
  const int t = threadIdx.x;
  const size_t base = (size_t)blockIdx.x * DM;
  u16x4 raw = ((const u16x4*)(in + base))[t];
  float v0 = bf2f(raw[0]), v1 = bf2f(raw[1]), v2 = bf2f(raw[2]), v3 = bf2f(raw[3]);
  float s = v0+v1+v2+v3;
#pragma unroll
  for (int d=1; d<64; d<<=1) s += __shfl_xor(s, d, 64);
  if ((t&63)==0) red[t>>6] = s;
  __syncthreads();
  float mean = (red[0]+red[1]+red[2]+red[3]) * (1.f/DM);
  __syncthreads();
  float d0=v0-mean, d1=v1-mean, d2=v2-mean, d3=v3-mean;
  float q = d0*d0+d1*d1+d2*d2+d3*d3;
#pragma unroll
  for (int d=1; d<64; d<<=1) q += __shfl_xor(q, d, 64);
  if ((t&63)==0) red[t>>6] = q;
  __syncthreads();
  float var = (red[0]+red[1]+red[2]+red[3]) * (1.f/DM);
  float inv = rsqrtf(var + 1e-5f);
  float4 wv = ((const float4*)gw)[t];
  float4 bv = ((const float4*)gb)[t];
  float o0 = d0*inv*wv.x + bv.x;
  float o1 = d1*inv*wv.y + bv.y;
  float o2 = d2*inv*wv.z + bv.z;
  float o3 = d3*inv*wv.w + bv.w;
  if (OUTF) {
    float4 o; o.x=o0; o.y=o1; o.z=o2; o.w=o3;
    ((float4*)((float*)out + base))[t] = o;
  } else {
    u16x4 ub; ub[0]=f2bf(o0); ub[1]=f2bf(o1); ub[2]=f2bf(o2); ub[3]=f2bf(o3);
    ((u16x4*)((unsigned short*)out + base))[t] = ub;
  }
}

// single fused cast dispatch: 9728 blocks, 1024 float4 per block
// ranges: x[0,7680) wq[7680,7936) wk[7936,8192) wv[8192,8448)
//         wo[8448,8704) w1[8704,9216) w2[9216,9728)
__global__ __launch_bounds__(256)
void cast_all(const float* __restrict__ x,  const float* __restrict__ wq,
              const float* __restrict__ wk, const float* __restrict__ wv,
              const float* __restrict__ wo, const float* __restrict__ w1,
              const float* __restrict__ w2,
              unsigned short* __restrict__ xb, unsigned short* __restrict__ wqkvb,
              unsigned short* __restrict__ wob, unsigned short* __restrict__ w1b,
              unsigned short* __restrict__ w2b) {
  const int b = blockIdx.x;
  const float* src; unsigned short* dst; int off;
  if (b < 7680)      { src = x;  dst = xb;              off = b; }
  else if (b < 7936) { src = wq; dst = wqkvb;           off = b - 7680; }
  else if (b < 8192) { src = wk; dst = wqkvb + 1048576; off = b - 7936; }
  else if (b < 8448) { src = wv; dst = wqkvb + 2097152; off = b - 8192; }
  else if (b < 8704) { src = wo; dst = wob;             off = b - 8448; }
  else if (b < 9216) { src = w1; dst = w1b;             off = b - 8704; }
  else               { src = w2; dst = w2b;             off = b - 9216; }
  int i = off*1024 + threadIdx.x;
#pragma unroll
  for (int u=0; u<4; ++u, i += 256) {
    float4 v = ((const float4*)src)[i];
    u16x4 p; p[0]=f2bf(v.x); p[1]=f2bf(v.y); p[2]=f2bf(v.z); p[3]=f2bf(v.w);
    ((u16x4*)dst)[i] = p;
  }
}

extern "C" void kernel_launch(void* const* d_in, const int* in_sizes, int n_in,
                              void* d_out, int out_size, void* d_ws, size_t ws_size,
                              hipStream_t stream) {
  const float* x      = (const float*)d_in[0];
  const float* attsig = (const float*)d_in[1];
  const float* wq     = (const float*)d_in[2];
  const float* wk     = (const float*)d_in[3];
  const float* wv     = (const float*)d_in[4];
  const float* wo     = (const float*)d_in[5];
  const float* ln1w   = (const float*)d_in[6];
  const float* ln1b   = (const float*)d_in[7];
  const float* w1     = (const float*)d_in[8];
  const float* w2     = (const float*)d_in[9];
  const float* ln2w   = (const float*)d_in[10];
  const float* ln2b   = (const float*)d_in[11];

  char* ws = (char*)d_ws;
  unsigned short* xb    = (unsigned short*)(ws);              // 30720x1024 bf16 (x, then LN1 out)
  unsigned short* wqkvb = (unsigned short*)(ws + 62914560ull);// 3072x1024
  unsigned short* wob   = (unsigned short*)(ws + 69206016ull);// 1024x1024
  unsigned short* w1b   = (unsigned short*)(ws + 71303168ull);// 2048x1024
  unsigned short* w2b   = (unsigned short*)(ws + 75497472ull);// 1024x2048
  unsigned short* qkv   = (unsigned short*)(ws + 79691776ull);// 30720x3072 (later: f2b)
  unsigned short* h1    = (unsigned short*)(ws + 268435456ull);// 30720x2048 (first: o1b)
  float*          lpart = (float*)(ws + 394264576ull);        // 8192

  unsigned short* o1b = h1;    // 30720x1024 bf16, dead before FFN1 writes h1
  unsigned short* f2b = qkv;   // 30720x1024 bf16, qkv dead after O-proj

  float* outf = (float*)d_out;
  float* loss = outf + (size_t)M_TOK*DM;

  cast_all<<<9728,256,0,stream>>>(x, wq, wk, wv, wo, w1, w2,
                                  xb, wqkvb, wob, w1b, w2b);

  // QKV: [30720,1024] @ [3072,1024]^T -> bf16 [30720,3072]
  gemm256<0><<<NTM*(NQKV/256), 512, 0, stream>>>(xb, DM, wqkvb, DM, qkv, NQKV, nullptr, DM);

  attn_kernel<<<BBATCH*NH, 256, 0, stream>>>(qkv, attsig, lpart);
  reduce_loss<<<1,256,0,stream>>>(lpart, loss);

  // o1b = bf16(ctx @ wo^T + xb)
  gemm256<3><<<NTM*(DM/256), 512, 0, stream>>>(qkv, NQKV, wob, DM, o1b, DM, xb, DM);
  // LN1: o1b -> xb (bf16)
  ln_bf<0><<<M_TOK,256,0,stream>>>(o1b, ln1w, ln1b, xb);
  // h1 = relu(xb @ w1^T)  (overwrites o1b region; o1b dead)
  gemm256<2><<<NTM*(DFF/256), 512, 0, stream>>>(xb, DM, w1b, DM, h1, DFF, nullptr, DM);
  // f2b = bf16(h1 @ w2^T + xb)
  gemm256<3><<<NTM*(DM/256), 512, 0, stream>>>(h1, DFF, w2b, DFF, f2b, DM, xb, DFF);
  // LN2: f2b -> d_out (fp32)
  ln_bf<1><<<M_TOK,256,0,stream>>>(f2b, ln2w, ln2b, outf);
}

// Round 8
// 832.917 us; speedup vs baseline: 1.9747x; 1.9747x over previous
//
#include <hip/hip_runtime.h>
#include <hip/hip_bf16.h>
#include <cstdint>

#define DM   1024
#define DFF  2048
#define NH   16
#define DK   64
#define BBATCH 512
#define LSEQ 60
#define M_TOK (BBATCH*LSEQ)   // 30720
#define NQKV (3*DM)           // 3072
#define NTM  120              // M_TOK / 256

typedef __attribute__((ext_vector_type(8))) short bf16x8;
typedef __attribute__((ext_vector_type(4))) float f32x4;
typedef __attribute__((ext_vector_type(8))) unsigned short u16x8;
typedef __attribute__((ext_vector_type(4))) unsigned short u16x4;

__device__ __forceinline__ unsigned short f2bf(float f) {
  union { float f; unsigned u; } x; x.f = f;
  unsigned r = x.u + 0x7fffu + ((x.u >> 16) & 1u);   // RNE
  return (unsigned short)(r >> 16);
}
__device__ __forceinline__ float bf2f(unsigned short u) {
  union { unsigned u; float f; } x; x.u = ((unsigned)u) << 16;
  return x.f;
}

__device__ __forceinline__ void gload_lds16(const void* g, void* l) {
  __builtin_amdgcn_global_load_lds(
      (const __attribute__((address_space(1))) unsigned int*)g,
      (__attribute__((address_space(3))) unsigned int*)l, 16, 0, 0);
}

// LDS short-offsets: A buffers 256x64 bf16 (16384 shorts), B buffers 128x64
#define A0S 0
#define A1S 16384
#define B0S 32768
#define B1S 40960

// 256x128 tile, BK=64, 8 waves as 4M x 2N (wave output 64x64 -> acc=64 regs).
// 2-phase/K-tile full-tile register read-ahead: read T(kt+1) frags,
// lgkmcnt(15) [drain prev frag set; field caps at 15] + barrier, re-stage
// freed buffer, MFMA current set. Unified-reg demand ~217 < 256 (r7
// post-mortem: 512-thread block caps at 256 regs/wave; 128x64-wave
// geometry could not fit read-ahead -> spill).
// MODE 0: C bf16   MODE 2: C bf16 = relu(acc)
// MODE 3: C bf16 = acc + bf16_residual[row*ldc+col]
template<int MODE>
__global__ __launch_bounds__(512, 2)
void gemm256(const unsigned short* __restrict__ A, int lda,
             const unsigned short* __restrict__ B, int ldb,
             void* __restrict__ Cv, int ldc,
             const void* __restrict__ Resv, int K) {
  __shared__ unsigned short sm[49152];   // 96 KB: A0|A1|B0|B1
  const int t  = threadIdx.x;
  const int l  = t & 63, w = t >> 6;
  const int lo = l & 15, hi = l >> 4;
  const int wr = w >> 1, wc = w & 1;
  const int swz = (lo & 7) << 4;

  const int nwg = (int)gridDim.x;
  int wg = (int)blockIdx.x;
  wg = (wg & 7) * (nwg >> 3) + (wg >> 3);          // XCD swizzle (grid%8==0)
  const int ng  = wg / (NTM*4);
  const int rem = wg - ng*(NTM*4);
  const long row0 = (long)(rem >> 2) * 256;
  const long col0 = (long)(ng*4 + (rem & 3)) * 128;

  // staging geometry: thread t stages 16B rows (t>>3) + 64*pass, col
  // inverse-swizzled so linear LDS + swizzled read match (rule #21)
  const int scol = ((t & 7) ^ ((t >> 3) & 7)) * 8;
  const unsigned short* pa = A + (size_t)(row0 + (t>>3))*lda + scol;
  const unsigned short* pb = B + (size_t)(col0 + (t>>3))*ldb + scol;
  const size_t lda64 = (size_t)64*lda, ldb64 = (size_t)64*ldb;
  const int dst = t*8;   // shorts: t*16 bytes

#define STAGE(bufA, bufB, kt) do { \
    const unsigned short* _sa = pa + (size_t)(kt)*64; \
    gload_lds16(_sa,           &sm[(bufA) + dst]); \
    gload_lds16(_sa + lda64,   &sm[(bufA) + 4096 + dst]); \
    gload_lds16(_sa + 2*lda64, &sm[(bufA) + 8192 + dst]); \
    gload_lds16(_sa + 3*lda64, &sm[(bufA) + 12288 + dst]); \
    const unsigned short* _sb = pb + (size_t)(kt)*64; \
    gload_lds16(_sb,           &sm[(bufB) + dst]); \
    gload_lds16(_sb + ldb64,   &sm[(bufB) + 4096 + dst]); \
  } while(0)
#define RDF(fa, fb, bufA, bufB) do { \
  _Pragma("unroll") for (int n=0;n<4;++n) \
  _Pragma("unroll") for (int ks=0;ks<2;++ks) \
    fb[n][ks] = *(const bf16x8*)((const char*)sm + (bufB)*2 + \
        (wc*64 + n*16 + lo)*128 + ((((ks)<<6) | (hi<<4)) ^ swz)); \
  _Pragma("unroll") for (int m=0;m<4;++m) \
  _Pragma("unroll") for (int ks=0;ks<2;++ks) \
    fa[m][ks] = *(const bf16x8*)((const char*)sm + (bufA)*2 + \
        (wr*64 + m*16 + lo)*128 + ((((ks)<<6) | (hi<<4)) ^ swz)); \
  } while(0)
#define MFMA32(fa, fb) do { \
  _Pragma("unroll") for (int m=0;m<4;++m) \
  _Pragma("unroll") for (int n=0;n<4;++n) \
  _Pragma("unroll") for (int ks=0;ks<2;++ks) \
    acc[m][n] = __builtin_amdgcn_mfma_f32_16x16x32_bf16(fa[m][ks], fb[n][ks], acc[m][n], 0,0,0); \
  } while(0)
#define BAR __builtin_amdgcn_s_barrier()
#define VMC(n) asm volatile("s_waitcnt vmcnt(" #n ")" ::: "memory")
#define LGK15 asm volatile("s_waitcnt lgkmcnt(15)" ::: "memory")
#define P1S __builtin_amdgcn_s_setprio(1)
#define P0S __builtin_amdgcn_s_setprio(0)

  f32x4 acc[4][4];
#pragma unroll
  for (int m=0;m<4;++m)
#pragma unroll
    for (int n=0;n<4;++n) acc[m][n] = (f32x4){0.f,0.f,0.f,0.f};

  const int nkt = K >> 6;                // even, >= 4
  bf16x8 f0a[4][2], f0b[4][2], f1a[4][2], f1b[4][2];

  // prologue: stage T0,T1; wait T0; read F0
  STAGE(A0S, B0S, 0);
  STAGE(A1S, B1S, 1);
  VMC(6);
  BAR;
  RDF(f0a, f0b, A0S, B0S);

  for (int kt = 0; kt + 2 < nkt; kt += 2) {
    // half A: consume F0=T(kt), read F1=T(kt+1), restage buf0 with T(kt+2)
    VMC(0);                    // T(kt+1) staged by all? (own loads done)
    BAR;                       // -> every wave's stage of buf1 drained
    RDF(f1a, f1b, A1S, B1S);
    LGK15;                     // F0 reads (older) complete across wave
    BAR;                       // -> all waves done reading buf0
    STAGE(A0S, B0S, kt+2);
    P1S; MFMA32(f0a, f0b); P0S;
    // half B: consume F1, read F0=T(kt+2), restage buf1 with T(kt+3)
    VMC(0);
    BAR;
    RDF(f0a, f0b, A0S, B0S);
    LGK15;
    BAR;
    STAGE(A1S, B1S, kt+3);
    P1S; MFMA32(f1a, f1b); P0S;
  }

  // peel: f0 = T(nkt-2) already read; buf1 holds T(nkt-1)
  VMC(0);
  BAR;
  RDF(f1a, f1b, A1S, B1S);
  P1S; MFMA32(f0a, f0b); P0S;   // compiler inserts counted lgkmcnt
  P1S; MFMA32(f1a, f1b); P0S;

  // epilogue
#pragma unroll
  for (int m=0;m<4;++m) {
#pragma unroll
    for (int r=0;r<4;++r) {
      const long row = row0 + wr*64 + m*16 + hi*4 + r;
      const size_t base = (size_t)row * ldc;
#pragma unroll
      for (int n=0;n<4;++n) {
        const long col = col0 + wc*64 + n*16 + lo;
        const float v = acc[m][n][r];
        if (MODE == 0) {
          ((unsigned short*)Cv)[base + col] = f2bf(v);
        } else if (MODE == 2) {
          ((unsigned short*)Cv)[base + col] = f2bf(v > 0.f ? v : 0.f);
        } else {
          const unsigned short* R16 = (const unsigned short*)Resv;
          ((unsigned short*)Cv)[base + col] = f2bf(v + bf2f(R16[base + col]));
        }
      }
    }
  }
#undef STAGE
#undef RDF
#undef MFMA32
#undef BAR
#undef VMC
#undef LGK15
#undef P1S
#undef P0S
}

// One block per (b,h). qkv: [M_TOK][3072] bf16 (Q|K|V). ctx written in-place over Q cols.
__global__ __launch_bounds__(256)
void attn_kernel(unsigned short* qkv, const float* __restrict__ att_sig,
                 float* __restrict__ loss_part) {
  __shared__ unsigned short qs[64*64], ks[64*64], vts[64*64], as2[64*64];
  __shared__ float red[4];
  const int bid = blockIdx.x;
  const int b = bid >> 4, h = bid & 15;
  const int t = threadIdx.x;
  const int l = t & 63, w = t >> 6, lo = l & 15, hi = l >> 4;

#pragma unroll
  for (int p=0;p<2;++p) {
    int row = p*32 + (t>>3);
    int d0  = (t&7)*8;
    u16x8 zq = {0,0,0,0,0,0,0,0}; u16x8 zk = zq; u16x8 zv = zq;
    if (row < LSEQ) {
      size_t g = (size_t)(b*LSEQ + row)*NQKV + h*DK + d0;
      zq = *(const u16x8*)(qkv + g);
      zk = *(const u16x8*)(qkv + g + DM);
      zv = *(const u16x8*)(qkv + g + 2*DM);
    }
    *(u16x8*)&qs[row*64 + d0] = zq;
    *(u16x8*)&ks[row*64 + d0] = zk;
#pragma unroll
    for (int j=0;j<8;++j) vts[(d0+j)*64 + row] = zv[j];
  }
  __syncthreads();

  f32x4 zero4 = {0.f,0.f,0.f,0.f};
  f32x4 sacc[4];
#pragma unroll
  for (int ct=0;ct<4;++ct) sacc[ct] = zero4;
  bf16x8 aq[2];
  aq[0] = *(const bf16x8*)&qs[(w*16+lo)*64 + hi*8];
  aq[1] = *(const bf16x8*)&qs[(w*16+lo)*64 + 32 + hi*8];
#pragma unroll
  for (int ct=0;ct<4;++ct)
#pragma unroll
    for (int kk=0;kk<2;++kk) {
      bf16x8 bk = *(const bf16x8*)&ks[(ct*16+lo)*64 + kk*32 + hi*8];
      sacc[ct] = __builtin_amdgcn_mfma_f32_16x16x32_bf16(aq[kk], bk, sacc[ct], 0,0,0);
    }

  float lloss = 0.f;
  const float SC = 0.125f;
#pragma unroll
  for (int r=0;r<4;++r) {
    int row = w*16 + hi*4 + r;
    float v0 = sacc[0][r]*SC, v1 = sacc[1][r]*SC, v2 = sacc[2][r]*SC;
    float v3 = (lo < 12) ? sacc[3][r]*SC : -__builtin_inff();
    float mx = fmaxf(fmaxf(v0,v1), fmaxf(v2,v3));
#pragma unroll
    for (int d=1; d<16; d<<=1) mx = fmaxf(mx, __shfl_xor(mx, d, 64));
    float p0=__expf(v0-mx), p1=__expf(v1-mx), p2=__expf(v2-mx), p3=__expf(v3-mx);
    float sm = p0+p1+p2+p3;
#pragma unroll
    for (int d=1; d<16; d<<=1) sm += __shfl_xor(sm, d, 64);
    float inv = 1.0f / sm;
    float a0=p0*inv, a1=p1*inv, a2=p2*inv, a3=p3*inv;
    if (row < LSEQ) {
      float df;
      df = a0 - att_sig[row*LSEQ + lo];       lloss += df*df;
      df = a1 - att_sig[row*LSEQ + 16 + lo];  lloss += df*df;
      df = a2 - att_sig[row*LSEQ + 32 + lo];  lloss += df*df;
      if (lo < 12) { df = a3 - att_sig[row*LSEQ + 48 + lo]; lloss += df*df; }
    }
    as2[row*64 + lo]      = f2bf(a0);
    as2[row*64 + 16 + lo] = f2bf(a1);
    as2[row*64 + 32 + lo] = f2bf(a2);
    as2[row*64 + 48 + lo] = f2bf(a3);
  }
  __syncthreads();

  f32x4 cacc[4];
#pragma unroll
  for (int n=0;n<4;++n) cacc[n] = zero4;
  bf16x8 ap[2];
  ap[0] = *(const bf16x8*)&as2[(w*16+lo)*64 + hi*8];
  ap[1] = *(const bf16x8*)&as2[(w*16+lo)*64 + 32 + hi*8];
#pragma unroll
  for (int n=0;n<4;++n)
#pragma unroll
    for (int kk=0;kk<2;++kk) {
      bf16x8 bv = *(const bf16x8*)&vts[(n*16+lo)*64 + kk*32 + hi*8];
      cacc[n] = __builtin_amdgcn_mfma_f32_16x16x32_bf16(ap[kk], bv, cacc[n], 0,0,0);
    }
#pragma unroll
  for (int r=0;r<4;++r) {
    int row = w*16 + hi*4 + r;
    if (row < LSEQ) {
      size_t g = (size_t)(b*LSEQ + row)*NQKV + h*DK;
#pragma unroll
      for (int n=0;n<4;++n)
        qkv[g + n*16 + lo] = f2bf(cacc[n][r]);
    }
  }

#pragma unroll
  for (int d=1; d<64; d<<=1) lloss += __shfl_xor(lloss, d, 64);
  if (l == 0) red[w] = lloss;
  __syncthreads();
  if (t == 0) loss_part[bid] = red[0]+red[1]+red[2]+red[3];
}

__global__ __launch_bounds__(256)
void reduce_loss(const float* __restrict__ part, float* __restrict__ out) {
  __shared__ float red[4];
  float s = 0.f;
  for (int i = threadIdx.x; i < BBATCH*NH; i += 256) s += part[i];
#pragma unroll
  for (int d=1; d<64; d<<=1) s += __shfl_xor(s, d, 64);
  if ((threadIdx.x & 63) == 0) red[threadIdx.x >> 6] = s;
  __syncthreads();
  if (threadIdx.x == 0) out[0] = red[0]+red[1]+red[2]+red[3];
}

// Row LayerNorm, bf16 input. OUTF=0: write bf16; OUTF=1: write fp32.
template<int OUTF>
__global__ __launch_bounds__(256)
void ln_bf(const unsigned short* __restrict__ in, const float* __restrict__ gw,
           const float* __restrict__ gb, void* __restrict__ out) {
  __shared__ float red[4];
  const int t = threadIdx.x;
  const size_t base = (size_t)blockIdx.x * DM;
  u16x4 raw = ((const u16x4*)(in + base))[t];
  float v0 = bf2f(raw[0]), v1 = bf2f(raw[1]), v2 = bf2f(raw[2]), v3 = bf2f(raw[3]);
  float s = v0+v1+v2+v3;
#pragma unroll
  for (int d=1; d<64; d<<=1) s += __shfl_xor(s, d, 64);
  if ((t&63)==0) red[t>>6] = s;
  __syncthreads();
  float mean = (red[0]+red[1]+red[2]+red[3]) * (1.f/DM);
  __syncthreads();
  float d0=v0-mean, d1=v1-mean, d2=v2-mean, d3=v3-mean;
  float q = d0*d0+d1*d1+d2*d2+d3*d3;
#pragma unroll
  for (int d=1; d<64; d<<=1) q += __shfl_xor(q, d, 64);
  if ((t&63)==0) red[t>>6] = q;
  __syncthreads();
  float var = (red[0]+red[1]+red[2]+red[3]) * (1.f/DM);
  float inv = rsqrtf(var + 1e-5f);
  float4 wv = ((const float4*)gw)[t];
  float4 bv = ((const float4*)gb)[t];
  float o0 = d0*inv*wv.x + bv.x;
  float o1 = d1*inv*wv.y + bv.y;
  float o2 = d2*inv*wv.z + bv.z;
  float o3 = d3*inv*wv.w + bv.w;
  if (OUTF) {
    float4 o; o.x=o0; o.y=o1; o.z=o2; o.w=o3;
    ((float4*)((float*)out + base))[t] = o;
  } else {
    u16x4 ub; ub[0]=f2bf(o0); ub[1]=f2bf(o1); ub[2]=f2bf(o2); ub[3]=f2bf(o3);
    ((u16x4*)((unsigned short*)out + base))[t] = ub;
  }
}

// single fused cast dispatch: 9728 blocks, 1024 float4 per block
// ranges: x[0,7680) wq[7680,7936) wk[7936,8192) wv[8192,8448)
//         wo[8448,8704) w1[8704,9216) w2[9216,9728)
__global__ __launch_bounds__(256)
void cast_all(const float* __restrict__ x,  const float* __restrict__ wq,
              const float* __restrict__ wk, const float* __restrict__ wv,
              const float* __restrict__ wo, const float* __restrict__ w1,
              const float* __restrict__ w2,
              unsigned short* __restrict__ xb, unsigned short* __restrict__ wqkvb,
              unsigned short* __restrict__ wob, unsigned short* __restrict__ w1b,
              unsigned short* __restrict__ w2b) {
  const int b = blockIdx.x;
  const float* src; unsigned short* dst; int off;
  if (b < 7680)      { src = x;  dst = xb;              off = b; }
  else if (b < 7936) { src = wq; dst = wqkvb;           off = b - 7680; }
  else if (b < 8192) { src = wk; dst = wqkvb + 1048576; off = b - 7936; }
  else if (b < 8448) { src = wv; dst = wqkvb + 2097152; off = b - 8192; }
  else if (b < 8704) { src = wo; dst = wob;             off = b - 8448; }
  else if (b < 9216) { src = w1; dst = w1b;             off = b - 8704; }
  else               { src = w2; dst = w2b;             off = b - 9216; }
  int i = off*1024 + threadIdx.x;
#pragma unroll
  for (int u=0; u<4; ++u, i += 256) {
    float4 v = ((const float4*)src)[i];
    u16x4 p; p[0]=f2bf(v.x); p[1]=f2bf(v.y); p[2]=f2bf(v.z); p[3]=f2bf(v.w);
    ((u16x4*)dst)[i] = p;
  }
}

extern "C" void kernel_launch(void* const* d_in, const int* in_sizes, int n_in,
                              void* d_out, int out_size, void* d_ws, size_t ws_size,
                              hipStream_t stream) {
  const float* x      = (const float*)d_in[0];
  const float* attsig = (const float*)d_in[1];
  const float* wq     = (const float*)d_in[2];
  const float* wk     = (const float*)d_in[3];
  const float* wv     = (const float*)d_in[4];
  const float* wo     = (const float*)d_in[5];
  const float* ln1w   = (const float*)d_in[6];
  const float* ln1b   = (const float*)d_in[7];
  const float* w1     = (const float*)d_in[8];
  const float* w2     = (const float*)d_in[9];
  const float* ln2w   = (const float*)d_in[10];
  const float* ln2b   = (const float*)d_in[11];

  char* ws = (char*)d_ws;
  unsigned short* xb    = (unsigned short*)(ws);              // 30720x1024 bf16 (x, then LN1 out)
  unsigned short* wqkvb = (unsigned short*)(ws + 62914560ull);// 3072x1024
  unsigned short* wob   = (unsigned short*)(ws + 69206016ull);// 1024x1024
  unsigned short* w1b   = (unsigned short*)(ws + 71303168ull);// 2048x1024
  unsigned short* w2b   = (unsigned short*)(ws + 75497472ull);// 1024x2048
  unsigned short* qkv   = (unsigned short*)(ws + 79691776ull);// 30720x3072 (later: f2b)
  unsigned short* h1    = (unsigned short*)(ws + 268435456ull);// 30720x2048 (first: o1b)
  float*          lpart = (float*)(ws + 394264576ull);        // 8192

  unsigned short* o1b = h1;    // 30720x1024 bf16, dead before FFN1 writes h1
  unsigned short* f2b = qkv;   // 30720x1024 bf16, qkv dead after O-proj

  float* outf = (float*)d_out;
  float* loss = outf + (size_t)M_TOK*DM;

  cast_all<<<9728,256,0,stream>>>(x, wq, wk, wv, wo, w1, w2,
                                  xb, wqkvb, wob, w1b, w2b);

  // QKV: [30720,1024] @ [3072,1024]^T -> bf16 [30720,3072]
  gemm256<0><<<NTM*(NQKV/128), 512, 0, stream>>>(xb, DM, wqkvb, DM, qkv, NQKV, nullptr, DM);

  attn_kernel<<<BBATCH*NH, 256, 0, stream>>>(qkv, attsig, lpart);
  reduce_loss<<<1,256,0,stream>>>(lpart, loss);

  // o1b = bf16(ctx @ wo^T + xb)
  gemm256<3><<<NTM*(DM/128), 512, 0, stream>>>(qkv, NQKV, wob, DM, o1b, DM, xb, DM);
  // LN1: o1b -> xb (bf16)
  ln_bf<0><<<M_TOK,256,0,stream>>>(o1b, ln1w, ln1b, xb);
  // h1 = relu(xb @ w1^T)
  gemm256<2><<<NTM*(DFF/128), 512, 0, stream>>>(xb, DM, w1b, DM, h1, DFF, nullptr, DM);
  // f2b = bf16(h1 @ w2^T + xb)
  gemm256<3><<<NTM*(DM/128), 512, 0, stream>>>(h1, DFF, w2b, DFF, f2b, DM, xb, DFF);
  // LN2: f2b -> d_out (fp32)
  ln_bf<1><<<M_TOK,256,0,stream>>>(f2b, ln2w, ln2b, outf);
}

// Round 9
// 711.442 us; speedup vs baseline: 2.3119x; 1.1707x over previous
//
#include <hip/hip_runtime.h>
#include <hip/hip_bf16.h>
#include <cstdint>

#define DM   1024
#define DFF  2048
#define NH   16
#define DK   64
#define BBATCH 512
#define LSEQ 60
#define M_TOK (BBATCH*LSEQ)   // 30720
#define NQKV (3*DM)           // 3072
#define NTM  120              // M_TOK / 256

typedef __attribute__((ext_vector_type(8))) short bf16x8;
typedef __attribute__((ext_vector_type(4))) float f32x4;
typedef __attribute__((ext_vector_type(8))) unsigned short u16x8;
typedef __attribute__((ext_vector_type(4))) unsigned short u16x4;

__device__ __forceinline__ unsigned short f2bf(float f) {
  union { float f; unsigned u; } x; x.f = f;
  unsigned r = x.u + 0x7fffu + ((x.u >> 16) & 1u);   // RNE
  return (unsigned short)(r >> 16);
}
__device__ __forceinline__ float bf2f(unsigned short u) {
  union { unsigned u; float f; } x; x.u = ((unsigned)u) << 16;
  return x.f;
}

__device__ __forceinline__ void gload_lds16(const void* g, void* l) {
  __builtin_amdgcn_global_load_lds(
      (const __attribute__((address_space(1))) unsigned int*)g,
      (__attribute__((address_space(3))) unsigned int*)l, 16, 0, 0);
}

template<int MO,int NO>
__device__ __forceinline__ void mf8(f32x4 (&acc)[8][4], const bf16x8 (&a)[4][2],
                                    const bf16x8 (&b)[2][2]) {
#pragma unroll
  for (int m=0;m<4;++m)
#pragma unroll
    for (int n=0;n<2;++n)
#pragma unroll
      for (int ks=0;ks<2;++ks)
        acc[MO+m][NO+n] = __builtin_amdgcn_mfma_f32_16x16x32_bf16(a[m][ks], b[n][ks], acc[MO+m][NO+n], 0,0,0);
}

// LDS short-offsets of the 4 32KB buffers (each holds a full 256x64 tile,
// rows 0..255 contiguous at 128B/row, st-swizzled byte ^= (row&7)<<4)
#define A0S 0
#define A1S 16384
#define B0S 32768
#define B1S 49152

// ===== r4 GEMM (best schedule: 208us QKV, MfmaUtil 40.5, VGPR 128, no
// spill) with bf16 epilogues. 256x256 tile, BK=64, 8 waves (2Mx4N),
// 2-K-tile-unrolled 8-phase counted-vmcnt schedule, all LDS offsets
// compile-time. nkt even, >=4.
// MODE 0: C bf16   MODE 2: C bf16 = relu(acc)
// MODE 3: C bf16 = acc + bf16_residual[row*ldc+col]
template<int MODE>
__global__ __launch_bounds__(512, 2)
void gemm256(const unsigned short* __restrict__ A, int lda,
             const unsigned short* __restrict__ B, int ldb,
             void* __restrict__ Cv, int ldc,
             const void* __restrict__ Resv, int K) {
  __shared__ unsigned short sm[65536];
  const int t  = threadIdx.x;
  const int l  = t & 63, w = t >> 6;
  const int lo = l & 15, hi = l >> 4;
  const int wr = w >> 2, wc = w & 3;
  const int swz = (lo & 7) << 4;

  const int nwg = (int)gridDim.x;
  int wg = (int)blockIdx.x;
  wg = (wg & 7) * (nwg >> 3) + (wg >> 3);
  const int ng  = wg / (NTM*4);
  const int rem = wg - ng*(NTM*4);
  const long row0 = (long)(rem >> 2) * 256;
  const long col0 = (long)(ng*4 + (rem & 3)) * 256;

  // per-thread stage-slot geometry: slot j=0 row, shared col (shorts)
  const int srow = w*16 + (l>>3);
  const int scol = ((l & 7) ^ (l >> 3)) * 8;
  const unsigned short* pa = A + (size_t)(row0 + srow)*lda + scol;
  const unsigned short* pb = B + (size_t)(col0 + srow)*ldb + scol;
  const size_t ldaj = (size_t)8*lda,  ldah = (size_t)128*lda;
  const size_t ldbj = (size_t)8*ldb,  ldbh = (size_t)128*ldb;
  const int dls = (w*2)*512;   // LDS short-offset of this wave's slot-0 chunk

#define STAGE_A(bufS, h, kt) do { \
    const unsigned short* _s = pa + (size_t)(h)*ldah + (size_t)(kt)*64; \
    gload_lds16(_s,        &sm[(bufS) + (h)*8192 + dls]); \
    gload_lds16(_s + ldaj, &sm[(bufS) + (h)*8192 + dls + 512]); \
  } while(0)
#define STAGE_B(bufS, h, kt) do { \
    const unsigned short* _s = pb + (size_t)(h)*ldbh + (size_t)(kt)*64; \
    gload_lds16(_s,        &sm[(bufS) + (h)*8192 + dls]); \
    gload_lds16(_s + ldbj, &sm[(bufS) + (h)*8192 + dls + 512]); \
  } while(0)
#define LDA8(dst, bufS, mbase) do { \
  _Pragma("unroll") for (int m=0;m<4;++m) \
  _Pragma("unroll") for (int ks=0;ks<2;++ks) \
    dst[m][ks] = *(const bf16x8*)((const char*)sm + (bufS)*2 + \
        (wr*128 + ((mbase)+m)*16 + lo)*128 + ((ks*64 + hi*16) ^ swz)); \
  } while(0)
#define LDB4(dst, bufS, nbase) do { \
  _Pragma("unroll") for (int n=0;n<2;++n) \
  _Pragma("unroll") for (int ks=0;ks<2;++ks) \
    dst[n][ks] = *(const bf16x8*)((const char*)sm + (bufS)*2 + \
        (wc*64 + ((nbase)+n)*16 + lo)*128 + ((ks*64 + hi*16) ^ swz)); \
  } while(0)
#define BAR __builtin_amdgcn_s_barrier()
#define LG0 asm volatile("s_waitcnt lgkmcnt(0)" ::: "memory")
#define LG8 asm volatile("s_waitcnt lgkmcnt(8)" ::: "memory")
#define P1S __builtin_amdgcn_s_setprio(1)
#define P0S __builtin_amdgcn_s_setprio(0)

  f32x4 acc[8][4];
#pragma unroll
  for (int m=0;m<8;++m)
#pragma unroll
    for (int n=0;n<4;++n) acc[m][n] = (f32x4){0.f,0.f,0.f,0.f};

  const int nkt = K >> 6;

  // prologue: tiles 0 -> A0/B0, 1 -> A1/B1
  STAGE_A(A0S, 0, 0); STAGE_A(A0S, 1, 0);
  STAGE_B(B0S, 0, 0); STAGE_B(B0S, 1, 0);
  STAGE_A(A1S, 0, 1); STAGE_A(A1S, 1, 1);
  STAGE_B(B1S, 0, 1); STAGE_B(B1S, 1, 1);
  asm volatile("s_waitcnt vmcnt(8)" ::: "memory");
  BAR;

  for (int kt = 0; kt + 2 < nkt; kt += 2) {
    bf16x8 a[4][2], b0[2][2], b2[2][2];
    // ---- P1 (tile kt, A0/B0, quad 0,0) ----
    LDA8(a, A0S, 0); LDB4(b0, B0S, 0);
    LG8; BAR; LG0;
    P1S; mf8<0,0>(acc, a, b0); P0S; BAR;
    // ---- P2 (quad 0,2) ----
    LDB4(b2, B0S, 2);
    BAR; LG0;
    P1S; mf8<0,2>(acc, a, b2); P0S; BAR;
    // ---- P3 (quad 4,0) ----
    LDA8(a, A0S, 4);
    STAGE_B(B0S, 0, kt+2);
    BAR; LG0;
    P1S; mf8<4,0>(acc, a, b0); P0S; BAR;
    // ---- P4 (quad 4,2) ----
    STAGE_B(B0S, 1, kt+2);
    asm volatile("s_waitcnt vmcnt(4)" ::: "memory");
    BAR;
    P1S; mf8<4,2>(acc, a, b2); P0S; BAR;
    // ---- P5 (tile kt+1, A1/B1, quad 0,0) ----
    LDA8(a, A1S, 0); LDB4(b0, B1S, 0);
    STAGE_A(A0S, 0, kt+2);
    LG8; BAR; LG0;
    P1S; mf8<0,0>(acc, a, b0); P0S; BAR;
    // ---- P6 (quad 0,2) ----
    LDB4(b2, B1S, 2);
    STAGE_A(A0S, 1, kt+2);
    BAR; LG0;
    P1S; mf8<0,2>(acc, a, b2); P0S; BAR;
    // ---- P7 (quad 4,0) ----
    LDA8(a, A1S, 4);
    STAGE_B(B1S, 0, kt+3); STAGE_B(B1S, 1, kt+3);
    BAR; LG0;
    P1S; mf8<4,0>(acc, a, b0); P0S; BAR;
    // ---- P8 (quad 4,2) ----
    STAGE_A(A1S, 0, kt+3); STAGE_A(A1S, 1, kt+3);
    asm volatile("s_waitcnt vmcnt(8)" ::: "memory");
    BAR;
    P1S; mf8<4,2>(acc, a, b2); P0S; BAR;
  }

  // peeled last two tiles (no staging)
  {
    bf16x8 a[4][2], b0[2][2], b2[2][2];
    LDA8(a, A0S, 0); LDB4(b0, B0S, 0);
    LG8; BAR; LG0; P1S; mf8<0,0>(acc, a, b0); P0S; BAR;
    LDB4(b2, B0S, 2);
    BAR; LG0; P1S; mf8<0,2>(acc, a, b2); P0S; BAR;
    LDA8(a, A0S, 4);
    BAR; LG0; P1S; mf8<4,0>(acc, a, b0); P0S; BAR;
    asm volatile("s_waitcnt vmcnt(0)" ::: "memory");
    BAR; P1S; mf8<4,2>(acc, a, b2); P0S; BAR;
    LDA8(a, A1S, 0); LDB4(b0, B1S, 0);
    LG8; BAR; LG0; P1S; mf8<0,0>(acc, a, b0); P0S; BAR;
    LDB4(b2, B1S, 2);
    BAR; LG0; P1S; mf8<0,2>(acc, a, b2); P0S; BAR;
    LDA8(a, A1S, 4);
    BAR; LG0; P1S; mf8<4,0>(acc, a, b0); P0S; BAR;
    P1S; mf8<4,2>(acc, a, b2); P0S;
  }

  // epilogue (all-bf16 outputs)
#pragma unroll
  for (int m=0;m<8;++m) {
#pragma unroll
    for (int r=0;r<4;++r) {
      const long row = row0 + wr*128 + m*16 + hi*4 + r;
      const size_t base = (size_t)row * ldc;
#pragma unroll
      for (int n=0;n<4;++n) {
        const long col = col0 + wc*64 + n*16 + lo;
        const float v = acc[m][n][r];
        if (MODE == 0) {
          ((unsigned short*)Cv)[base + col] = f2bf(v);
        } else if (MODE == 2) {
          ((unsigned short*)Cv)[base + col] = f2bf(v > 0.f ? v : 0.f);
        } else {
          const unsigned short* R16 = (const unsigned short*)Resv;
          ((unsigned short*)Cv)[base + col] = f2bf(v + bf2f(R16[base + col]));
        }
      }
    }
  }
#undef STAGE_A
#undef STAGE_B
#undef LDA8
#undef LDB4
#undef BAR
#undef LG0
#undef LG8
#undef P1S
#undef P0S
}

// One block per (b,h). qkv: [M_TOK][3072] bf16 (Q|K|V). ctx written in-place over Q cols.
__global__ __launch_bounds__(256)
void attn_kernel(unsigned short* qkv, const float* __restrict__ att_sig,
                 float* __restrict__ loss_part) {
  __shared__ unsigned short qs[64*64], ks[64*64], vts[64*64], as2[64*64];
  __shared__ float red[4];
  const int bid = blockIdx.x;
  const int b = bid >> 4, h = bid & 15;
  const int t = threadIdx.x;
  const int l = t & 63, w = t >> 6, lo = l & 15, hi = l >> 4;

#pragma unroll
  for (int p=0;p<2;++p) {
    int row = p*32 + (t>>3);
    int d0  = (t&7)*8;
    u16x8 zq = {0,0,0,0,0,0,0,0}; u16x8 zk = zq; u16x8 zv = zq;
    if (row < LSEQ) {
      size_t g = (size_t)(b*LSEQ + row)*NQKV + h*DK + d0;
      zq = *(const u16x8*)(qkv + g);
      zk = *(const u16x8*)(qkv + g + DM);
      zv = *(const u16x8*)(qkv + g + 2*DM);
    }
    *(u16x8*)&qs[row*64 + d0] = zq;
    *(u16x8*)&ks[row*64 + d0] = zk;
#pragma unroll
    for (int j=0;j<8;++j) vts[(d0+j)*64 + row] = zv[j];
  }
  __syncthreads();

  f32x4 zero4 = {0.f,0.f,0.f,0.f};
  f32x4 sacc[4];
#pragma unroll
  for (int ct=0;ct<4;++ct) sacc[ct] = zero4;
  bf16x8 aq[2];
  aq[0] = *(const bf16x8*)&qs[(w*16+lo)*64 + hi*8];
  aq[1] = *(const bf16x8*)&qs[(w*16+lo)*64 + 32 + hi*8];
#pragma unroll
  for (int ct=0;ct<4;++ct)
#pragma unroll
    for (int kk=0;kk<2;++kk) {
      bf16x8 bk = *(const bf16x8*)&ks[(ct*16+lo)*64 + kk*32 + hi*8];
      sacc[ct] = __builtin_amdgcn_mfma_f32_16x16x32_bf16(aq[kk], bk, sacc[ct], 0,0,0);
    }

  float lloss = 0.f;
  const float SC = 0.125f;
#pragma unroll
  for (int r=0;r<4;++r) {
    int row = w*16 + hi*4 + r;
    float v0 = sacc[0][r]*SC, v1 = sacc[1][r]*SC, v2 = sacc[2][r]*SC;
    float v3 = (lo < 12) ? sacc[3][r]*SC : -__builtin_inff();
    float mx = fmaxf(fmaxf(v0,v1), fmaxf(v2,v3));
#pragma unroll
    for (int d=1; d<16; d<<=1) mx = fmaxf(mx, __shfl_xor(mx, d, 64));
    float p0=__expf(v0-mx), p1=__expf(v1-mx), p2=__expf(v2-mx), p3=__expf(v3-mx);
    float sm = p0+p1+p2+p3;
#pragma unroll
    for (int d=1; d<16; d<<=1) sm += __shfl_xor(sm, d, 64);
    float inv = 1.0f / sm;
    float a0=p0*inv, a1=p1*inv, a2=p2*inv, a3=p3*inv;
    if (row < LSEQ) {
      float df;
      df = a0 - att_sig[row*LSEQ + lo];       lloss += df*df;
      df = a1 - att_sig[row*LSEQ + 16 + lo];  lloss += df*df;
      df = a2 - att_sig[row*LSEQ + 32 + lo];  lloss += df*df;
      if (lo < 12) { df = a3 - att_sig[row*LSEQ + 48 + lo]; lloss += df*df; }
    }
    as2[row*64 + lo]      = f2bf(a0);
    as2[row*64 + 16 + lo] = f2bf(a1);
    as2[row*64 + 32 + lo] = f2bf(a2);
    as2[row*64 + 48 + lo] = f2bf(a3);
  }
  __syncthreads();

  f32x4 cacc[4];
#pragma unroll
  for (int n=0;n<4;++n) cacc[n] = zero4;
  bf16x8 ap[2];
  ap[0] = *(const bf16x8*)&as2[(w*16+lo)*64 + hi*8];
  ap[1] = *(const bf16x8*)&as2[(w*16+lo)*64 + 32 + hi*8];
#pragma unroll
  for (int n=0;n<4;++n)
#pragma unroll
    for (int kk=0;kk<2;++kk) {
      bf16x8 bv = *(const bf16x8*)&vts[(n*16+lo)*64 + kk*32 + hi*8];
      cacc[n] = __builtin_amdgcn_mfma_f32_16x16x32_bf16(ap[kk], bv, cacc[n], 0,0,0);
    }
#pragma unroll
  for (int r=0;r<4;++r) {
    int row = w*16 + hi*4 + r;
    if (row < LSEQ) {
      size_t g = (size_t)(b*LSEQ + row)*NQKV + h*DK;
#pragma unroll
      for (int n=0;n<4;++n)
        qkv[g + n*16 + lo] = f2bf(cacc[n][r]);
    }
  }

#pragma unroll
  for (int d=1; d<64; d<<=1) lloss += __shfl_xor(lloss, d, 64);
  if (l == 0) red[w] = lloss;
  __syncthreads();
  if (t == 0) loss_part[bid] = red[0]+red[1]+red[2]+red[3];
}

__global__ __launch_bounds__(256)
void reduce_loss(const float* __restrict__ part, float* __restrict__ out) {
  __shared__ float red[4];
  float s = 0.f;
  for (int i = threadIdx.x; i < BBATCH*NH; i += 256) s += part[i];
#pragma unroll
  for (int d=1; d<64; d<<=1) s += __shfl_xor(s, d, 64);
  if ((threadIdx.x & 63) == 0) red[threadIdx.x >> 6] = s;
  __syncthreads();
  if (threadIdx.x == 0) out[0] = red[0]+red[1]+red[2]+red[3];
}

// Row LayerNorm, bf16 input. OUTF=0: write bf16; OUTF=1: write fp32.
template<int OUTF>
__global__ __launch_bounds__(256)
void ln_bf(const unsigned short* __restrict__ in, const float* __restrict__ gw,
           const float* __restrict__ gb, void* __restrict__ out) {
  __shared__ float red[4];
  const int t = threadIdx.x;
  const size_t base = (size_t)blockIdx.x * DM;
  u16x4 raw = ((const u16x4*)(in + base))[t];
  float v0 = bf2f(raw[0]), v1 = bf2f(raw[1]), v2 = bf2f(raw[2]), v3 = bf2f(raw[3]);
  float s = v0+v1+v2+v3;
#pragma unroll
  for (int d=1; d<64; d<<=1) s += __shfl_xor(s, d, 64);
  if ((t&63)==0) red[t>>6] = s;
  __syncthreads();
  float mean = (red[0]+red[1]+red[2]+red[3]) * (1.f/DM);
  __syncthreads();
  float d0=v0-mean, d1=v1-mean, d2=v2-mean, d3=v3-mean;
  float q = d0*d0+d1*d1+d2*d2+d3*d3;
#pragma unroll
  for (int d=1; d<64; d<<=1) q += __shfl_xor(q, d, 64);
  if ((t&63)==0) red[t>>6] = q;
  __syncthreads();
  float var = (red[0]+red[1]+red[2]+red[3]) * (1.f/DM);
  float inv = rsqrtf(var + 1e-5f);
  float4 wv = ((const float4*)gw)[t];
  float4 bv = ((const float4*)gb)[t];
  float o0 = d0*inv*wv.x + bv.x;
  float o1 = d1*inv*wv.y + bv.y;
  float o2 = d2*inv*wv.z + bv.z;
  float o3 = d3*inv*wv.w + bv.w;
  if (OUTF) {
    float4 o; o.x=o0; o.y=o1; o.z=o2; o.w=o3;
    ((float4*)((float*)out + base))[t] = o;
  } else {
    u16x4 ub; ub[0]=f2bf(o0); ub[1]=f2bf(o1); ub[2]=f2bf(o2); ub[3]=f2bf(o3);
    ((u16x4*)((unsigned short*)out + base))[t] = ub;
  }
}

// single fused cast dispatch: 9728 blocks, 1024 float4 per block
// ranges: x[0,7680) wq[7680,7936) wk[7936,8192) wv[8192,8448)
//         wo[8448,8704) w1[8704,9216) w2[9216,9728)
__global__ __launch_bounds__(256)
void cast_all(const float* __restrict__ x,  const float* __restrict__ wq,
              const float* __restrict__ wk, const float* __restrict__ wv,
              const float* __restrict__ wo, const float* __restrict__ w1,
              const float* __restrict__ w2,
              unsigned short* __restrict__ xb, unsigned short* __restrict__ wqkvb,
              unsigned short* __restrict__ wob, unsigned short* __restrict__ w1b,
              unsigned short* __restrict__ w2b) {
  const int b = blockIdx.x;
  const float* src; unsigned short* dst; int off;
  if (b < 7680)      { src = x;  dst = xb;              off = b; }
  else if (b < 7936) { src = wq; dst = wqkvb;           off = b - 7680; }
  else if (b < 8192) { src = wk; dst = wqkvb + 1048576; off = b - 7936; }
  else if (b < 8448) { src = wv; dst = wqkvb + 2097152; off = b - 8192; }
  else if (b < 8704) { src = wo; dst = wob;             off = b - 8448; }
  else if (b < 9216) { src = w1; dst = w1b;             off = b - 8704; }
  else               { src = w2; dst = w2b;             off = b - 9216; }
  int i = off*1024 + threadIdx.x;
#pragma unroll
  for (int u=0; u<4; ++u, i += 256) {
    float4 v = ((const float4*)src)[i];
    u16x4 p; p[0]=f2bf(v.x); p[1]=f2bf(v.y); p[2]=f2bf(v.z); p[3]=f2bf(v.w);
    ((u16x4*)dst)[i] = p;
  }
}

extern "C" void kernel_launch(void* const* d_in, const int* in_sizes, int n_in,
                              void* d_out, int out_size, void* d_ws, size_t ws_size,
                              hipStream_t stream) {
  const float* x      = (const float*)d_in[0];
  const float* attsig = (const float*)d_in[1];
  const float* wq     = (const float*)d_in[2];
  const float* wk     = (const float*)d_in[3];
  const float* wv     = (const float*)d_in[4];
  const float* wo     = (const float*)d_in[5];
  const float* ln1w   = (const float*)d_in[6];
  const float* ln1b   = (const float*)d_in[7];
  const float* w1     = (const float*)d_in[8];
  const float* w2     = (const float*)d_in[9];
  const float* ln2w   = (const float*)d_in[10];
  const float* ln2b   = (const float*)d_in[11];

  char* ws = (char*)d_ws;
  unsigned short* xb    = (unsigned short*)(ws);              // 30720x1024 bf16 (x, then LN1 out)
  unsigned short* wqkvb = (unsigned short*)(ws + 62914560ull);// 3072x1024
  unsigned short* wob   = (unsigned short*)(ws + 69206016ull);// 1024x1024
  unsigned short* w1b   = (unsigned short*)(ws + 71303168ull);// 2048x1024
  unsigned short* w2b   = (unsigned short*)(ws + 75497472ull);// 1024x2048
  unsigned short* qkv   = (unsigned short*)(ws + 79691776ull);// 30720x3072 (later: f2b)
  unsigned short* h1    = (unsigned short*)(ws + 268435456ull);// 30720x2048 (first: o1b)
  float*          lpart = (float*)(ws + 394264576ull);        // 8192

  unsigned short* o1b = h1;    // 30720x1024 bf16, dead before FFN1 writes h1
  unsigned short* f2b = qkv;   // 30720x1024 bf16, qkv dead after O-proj

  float* outf = (float*)d_out;
  float* loss = outf + (size_t)M_TOK*DM;

  cast_all<<<9728,256,0,stream>>>(x, wq, wk, wv, wo, w1, w2,
                                  xb, wqkvb, wob, w1b, w2b);

  // QKV: [30720,1024] @ [3072,1024]^T -> bf16 [30720,3072]
  gemm256<0><<<NTM*(NQKV/256), 512, 0, stream>>>(xb, DM, wqkvb, DM, qkv, NQKV, nullptr, DM);

  attn_kernel<<<BBATCH*NH, 256, 0, stream>>>(qkv, attsig, lpart);
  reduce_loss<<<1,256,0,stream>>>(lpart, loss);

  // o1b = bf16(ctx @ wo^T + xb)
  gemm256<3><<<NTM*(DM/256), 512, 0, stream>>>(qkv, NQKV, wob, DM, o1b, DM, xb, DM);
  // LN1: o1b -> xb (bf16)
  ln_bf<0><<<M_TOK,256,0,stream>>>(o1b, ln1w, ln1b, xb);
  // h1 = relu(xb @ w1^T)
  gemm256<2><<<NTM*(DFF/256), 512, 0, stream>>>(xb, DM, w1b, DM, h1, DFF, nullptr, DM);
  // f2b = bf16(h1 @ w2^T + xb)
  gemm256<3><<<NTM*(DM/256), 512, 0, stream>>>(h1, DFF, w2b, DFF, f2b, DM, xb, DFF);
  // LN2: f2b -> d_out (fp32)
  ln_bf<1><<<M_TOK,256,0,stream>>>(f2b, ln2w, ln2b, outf);
}